// Round 2
// baseline (45990.668 us; speedup 1.0000x reference)
//
#include <hip/hip_runtime.h>

// Seq2Seq LSTM (H=1024, B=64, T_enc=T_dec=512) as persistent-grid kernels.
// Inputs/outputs are FLOAT32 (per harness rule: cast per reference dtype);
// tf_mask is int32. Matmuls: f16 MFMA 16x16x32 (weights exact in f16), f32
// accumulate, f32 cell state. 256 WGs x 256 thr; WG w owns hidden units
// 4w..4w+3 (16 gate cols), all 64 batches. 2 grid barriers per timestep.

#define HD 1024
#define BB 64
#define TT 512
#define NWG 256
#define NTHR 256

typedef _Float16 f16x8 __attribute__((ext_vector_type(8)));
typedef float f32x4 __attribute__((ext_vector_type(4)));

struct KP {
  const float* seq;   // prev (enc) or nxt (dec), [B][T]
  const int* mask;    // [T] int32 (decoder only)
  const float* Wih0;  // [4096]
  const float* Whh0;  // [4096][1024]
  const float* b0;    // [4096]
  const float* Wih1;  // [4096][1024]
  const float* Whh1;  // [4096][1024]
  const float* b1;    // [4096]
  const float* fcW;   // [1024]
  const float* fcb;   // [1]
  _Float16* h0buf;    // [2][B][H] f16 ping-pong
  _Float16* h1buf;    // [2][B][H]
  float* c0buf;       // [B][H] f32 (enc->dec handoff)
  float* c1buf;       // [B][H]
  float* predpart;    // [2][16][B] f32
  int* flags;         // [NWG]
  float* out;         // [B][T] f32
};

__device__ __forceinline__ float sigm(float x) { return 1.0f / (1.0f + expf(-x)); }

// Grid barrier: per-WG flag (monotone epoch), wave0 polls all 256 flags.
__device__ __forceinline__ void gbar(int* flags, int epoch) {
  __syncthreads();
  if (threadIdx.x == 0) {
    __builtin_amdgcn_fence(__ATOMIC_RELEASE, "agent");
    __hip_atomic_store(&flags[blockIdx.x], epoch, __ATOMIC_RELAXED, __HIP_MEMORY_SCOPE_AGENT);
  }
  if (threadIdx.x < 64) {
#pragma unroll
    for (int i = 0; i < NWG / 64; ++i) {
      int idx = (int)threadIdx.x + i * 64;
      while (__hip_atomic_load(&flags[idx], __ATOMIC_RELAXED, __HIP_MEMORY_SCOPE_AGENT) < epoch)
        __builtin_amdgcn_s_sleep(1);
    }
  }
  __syncthreads();
  __builtin_amdgcn_fence(__ATOMIC_ACQUIRE, "agent");
}

__global__ void init_kernel(_Float16* h0, _Float16* h1, float* predpart, int* fe, int* fd) {
  int i = blockIdx.x * blockDim.x + threadIdx.x;
  int stride = gridDim.x * blockDim.x;
  for (int j = i; j < 2 * BB * HD; j += stride) {
    h0[j] = (_Float16)0.0f;
    h1[j] = (_Float16)0.0f;
  }
  for (int j = i; j < 2 * 16 * BB; j += stride) predpart[j] = 0.0f;
  if (i < NWG) {
    fe[i] = 0;
    fd[i] = 0;
  }
}

template <int IS_DEC>
__global__ __launch_bounds__(NTHR, 1) void seq_kernel(KP p) {
  // LDS: layer-1 weights (Wih1, Whh1), fragment-swizzled: [mat][kchunk][lane][8 f16]
  __shared__ _Float16 ldsW[2][32][64][8];  // 65536 B

  const int tid = threadIdx.x;
  const int wg = blockIdx.x;
  const int wave = tid >> 6;
  const int lane = tid & 63;
  const int n = lane & 15;      // MFMA col (N) / A row (M) index
  const int q = lane >> 4;      // quad
  const int gidx = n & 3;       // gate index within unit (i,f,g,o)
  const int u = n >> 2;         // local unit 0..3
  const int unitG = wg * 4 + u; // global hidden unit
  const int rowG = gidx * HD + unitG;  // row of W / bias for this lane's col
  const int koff = q * 8;
  const int arow = wave * 16 + n;      // batch row for A fragments

  // ---- one-time: stage layer-1 weights into LDS (f32 -> f16, swizzled) ----
  for (int g = tid; g < 4096; g += NTHR) {
    int mat = g >> 11;
    int gg = g & 2047;
    int kc = gg >> 6;
    int lv = gg & 63;
    int nn = lv & 15, qq = lv >> 4;
    int rG = (nn & 3) * HD + (wg * 4 + (nn >> 2));
    const float* src = (mat == 0 ? p.Wih1 : p.Whh1) + rG * HD + kc * 32 + qq * 8;
#pragma unroll
    for (int j = 0; j < 8; ++j) ldsW[mat][kc][lv][j] = (_Float16)src[j];
  }

  // ---- one-time: layer-0 hidden weights as register B-fragments (128 VGPRs) ----
  f16x8 wf0[32];
#pragma unroll
  for (int kc = 0; kc < 32; ++kc) {
    const float* src = p.Whh0 + rowG * HD + kc * 32 + koff;
    f16x8 v;
#pragma unroll
    for (int j = 0; j < 8; ++j) v[j] = (_Float16)src[j];
    wf0[kc] = v;
  }

  const float bias0 = p.b0[rowG];
  const float bias1 = p.b1[rowG];
  const float wih0 = p.Wih0[rowG];
  const float fcw = p.fcW[unitG];
  const float fcb = p.fcb[0];

  float c0r[4], c1r[4];
#pragma unroll
  for (int r = 0; r < 4; ++r) {
    if (IS_DEC) {
      int b = wave * 16 + q * 4 + r;
      c0r[r] = p.c0buf[b * HD + unitG];
      c1r[r] = p.c1buf[b * HD + unitG];
    } else {
      c0r[r] = 0.0f;
      c1r[r] = 0.0f;
    }
  }
  __syncthreads();

  int epoch = 1;
  for (int t = 0; t < TT; ++t) {
    const int wp = t & 1;
    _Float16* h0w = p.h0buf + wp * (BB * HD);
    const _Float16* h0r = p.h0buf + (1 - wp) * (BB * HD);
    _Float16* h1w = p.h1buf + wp * (BB * HD);
    const _Float16* h1r = p.h1buf + (1 - wp) * (BB * HD);

    // ================= layer 0 =================
    f32x4 acc = {0.0f, 0.0f, 0.0f, 0.0f};
    {
      const _Float16* Ap = h0r + arow * HD + koff;
#pragma unroll
      for (int kc = 0; kc < 32; ++kc) {
        f16x8 a = *(const f16x8*)(Ap + kc * 32);
        acc = __builtin_amdgcn_mfma_f32_16x16x32_f16(a, wf0[kc], acc, 0, 0, 0);
      }
    }

    float xv[4];
    if (!IS_DEC) {
#pragma unroll
      for (int r = 0; r < 4; ++r) {
        int b = wave * 16 + q * 4 + r;
        xv[r] = p.seq[b * TT + t];
      }
    } else {
      if (t == 0) {
#pragma unroll
        for (int r = 0; r < 4; ++r) xv[r] = 0.0f;
      } else if (p.mask[t - 1] != 0) {
#pragma unroll
        for (int r = 0; r < 4; ++r) {
          int b = wave * 16 + q * 4 + r;
          xv[r] = p.seq[b * TT + (t - 1)];
        }
      } else {
        const float* pp = p.predpart + ((t - 1) & 1) * (16 * BB);
#pragma unroll
        for (int r = 0; r < 4; ++r) {
          int b = wave * 16 + q * 4 + r;
          float s = 0.0f;
#pragma unroll
          for (int j3 = 0; j3 < 4; ++j3) s += pp[(gidx * 4 + j3) * BB + b];
          s += __shfl_xor(s, 1);
          s += __shfl_xor(s, 2);
          xv[r] = s + fcb;
        }
      }
      // WG0 writes out[:, t-1] (pred of previous step, now fully reduced)
      if (wg == 0 && t > 0 && tid < BB) {
        const float* pp = p.predpart + ((t - 1) & 1) * (16 * BB);
        float s = fcb;
#pragma unroll
        for (int j2 = 0; j2 < 16; ++j2) s += pp[j2 * BB + tid];
        p.out[tid * TT + (t - 1)] = s;
      }
    }

#pragma unroll
    for (int r = 0; r < 4; ++r) {
      float v = acc[r] + bias0 + xv[r] * wih0;
      float v1 = __shfl_xor(v, 1);
      float v2 = __shfl_xor(v, 2);
      float v3 = __shfl_xor(v, 3);
      float gi = (gidx == 0) ? v : (gidx == 1) ? v1 : (gidx == 2) ? v2 : v3;
      float gf = (gidx == 1) ? v : (gidx == 0) ? v1 : (gidx == 3) ? v2 : v3;
      float gg = (gidx == 2) ? v : (gidx == 3) ? v1 : (gidx == 0) ? v2 : v3;
      float go = (gidx == 3) ? v : (gidx == 2) ? v1 : (gidx == 1) ? v2 : v3;
      float cn = sigm(gf) * c0r[r] + sigm(gi) * tanhf(gg);
      float hn = sigm(go) * tanhf(cn);
      c0r[r] = cn;
      if (gidx == 0) {
        int b = wave * 16 + q * 4 + r;
        h0w[b * HD + unitG] = (_Float16)hn;
      }
    }
    gbar(p.flags, epoch++);

    // ================= layer 1 =================
    f32x4 acc2 = {0.0f, 0.0f, 0.0f, 0.0f};
    {
      const _Float16* Ax = h0w + arow * HD + koff;  // x-input = h0(t)
      const _Float16* Ah = h1r + arow * HD + koff;  // h-input = h1(t-1)
#pragma unroll
      for (int kc = 0; kc < 32; ++kc) {
        f16x8 a0 = *(const f16x8*)(Ax + kc * 32);
        f16x8 b0 = *(const f16x8*)(&ldsW[0][kc][lane][0]);
        acc2 = __builtin_amdgcn_mfma_f32_16x16x32_f16(a0, b0, acc2, 0, 0, 0);
        f16x8 a1 = *(const f16x8*)(Ah + kc * 32);
        f16x8 b1 = *(const f16x8*)(&ldsW[1][kc][lane][0]);
        acc2 = __builtin_amdgcn_mfma_f32_16x16x32_f16(a1, b1, acc2, 0, 0, 0);
      }
    }

    // zero the OTHER predpart parity (safe: its readers finished last phase)
    if (IS_DEC && wg == 0) {
      float* pz = p.predpart + (1 - (t & 1)) * (16 * BB);
      for (int i2 = tid; i2 < 16 * BB; i2 += NTHR) pz[i2] = 0.0f;
    }

#pragma unroll
    for (int r = 0; r < 4; ++r) {
      float v = acc2[r] + bias1;
      float v1 = __shfl_xor(v, 1);
      float v2 = __shfl_xor(v, 2);
      float v3 = __shfl_xor(v, 3);
      float gi = (gidx == 0) ? v : (gidx == 1) ? v1 : (gidx == 2) ? v2 : v3;
      float gf = (gidx == 1) ? v : (gidx == 0) ? v1 : (gidx == 3) ? v2 : v3;
      float gg = (gidx == 2) ? v : (gidx == 3) ? v1 : (gidx == 0) ? v2 : v3;
      float go = (gidx == 3) ? v : (gidx == 2) ? v1 : (gidx == 1) ? v2 : v3;
      float cn = sigm(gf) * c1r[r] + sigm(gi) * tanhf(gg);
      float hn = sigm(go) * tanhf(cn);
      c1r[r] = cn;
      if (gidx == 0) {
        int b = wave * 16 + q * 4 + r;
        h1w[b * HD + unitG] = (_Float16)hn;
      }
      if (IS_DEC) {
        // fc partial: sum over this WG's 4 units, 16-group atomics
        float pl = (gidx == 0) ? hn * fcw : 0.0f;
        pl += __shfl_xor(pl, 1);
        pl += __shfl_xor(pl, 2);
        pl += __shfl_xor(pl, 4);
        pl += __shfl_xor(pl, 8);
        if (n == 0) {
          int b = wave * 16 + q * 4 + r;
          atomicAdd(p.predpart + (t & 1) * (16 * BB) + (wg >> 4) * BB + b, pl);
        }
      }
    }
    gbar(p.flags, epoch++);
  }

  if (!IS_DEC) {
    // hand final c-states to the decoder (final h is in parity-1 h bufs,
    // which is exactly what the decoder reads at its t=0 since TT is even)
    if (gidx == 0) {
#pragma unroll
      for (int r = 0; r < 4; ++r) {
        int b = wave * 16 + q * 4 + r;
        p.c0buf[b * HD + unitG] = c0r[r];
        p.c1buf[b * HD + unitG] = c1r[r];
      }
    }
  } else {
    // final pred (t = 511)
    if (wg == 0 && tid < BB) {
      const float* pp = p.predpart + ((TT - 1) & 1) * (16 * BB);
      float s = fcb;
#pragma unroll
      for (int j2 = 0; j2 < 16; ++j2) s += pp[j2 * BB + tid];
      p.out[tid * TT + (TT - 1)] = s;
    }
  }
}

extern "C" void kernel_launch(void* const* d_in, const int* in_sizes, int n_in,
                              void* d_out, int out_size, void* d_ws, size_t ws_size,
                              hipStream_t stream) {
  (void)in_sizes; (void)n_in; (void)out_size; (void)ws_size;
  const float* prev = (const float*)d_in[0];
  const float* nxt = (const float*)d_in[1];
  const int* mask = (const int*)d_in[2];
  const float* eWih0 = (const float*)d_in[3];
  const float* eWhh0 = (const float*)d_in[4];
  const float* eb0 = (const float*)d_in[5];
  const float* eWih1 = (const float*)d_in[6];
  const float* eWhh1 = (const float*)d_in[7];
  const float* eb1 = (const float*)d_in[8];
  const float* dWih0 = (const float*)d_in[9];
  const float* dWhh0 = (const float*)d_in[10];
  const float* db0 = (const float*)d_in[11];
  const float* dWih1 = (const float*)d_in[12];
  const float* dWhh1 = (const float*)d_in[13];
  const float* db1 = (const float*)d_in[14];
  const float* fcW = (const float*)d_in[15];
  const float* fcb = (const float*)d_in[16];

  char* w = (char*)d_ws;
  _Float16* h0buf = (_Float16*)w; w += 2 * BB * HD * 2;
  _Float16* h1buf = (_Float16*)w; w += 2 * BB * HD * 2;
  float* c0buf = (float*)w; w += BB * HD * 4;
  float* c1buf = (float*)w; w += BB * HD * 4;
  float* predpart = (float*)w; w += 2 * 16 * BB * 4;
  int* flagsE = (int*)w; w += NWG * 4;
  int* flagsD = (int*)w; w += NWG * 4;

  init_kernel<<<dim3(128), dim3(256), 0, stream>>>(h0buf, h1buf, predpart, flagsE, flagsD);

  KP pe;
  pe.seq = prev; pe.mask = mask;
  pe.Wih0 = eWih0; pe.Whh0 = eWhh0; pe.b0 = eb0;
  pe.Wih1 = eWih1; pe.Whh1 = eWhh1; pe.b1 = eb1;
  pe.fcW = fcW; pe.fcb = fcb;
  pe.h0buf = h0buf; pe.h1buf = h1buf;
  pe.c0buf = c0buf; pe.c1buf = c1buf;
  pe.predpart = predpart; pe.flags = flagsE;
  pe.out = (float*)d_out;
  seq_kernel<0><<<dim3(NWG), dim3(NTHR), 0, stream>>>(pe);

  KP pd = pe;
  pd.seq = nxt;
  pd.Wih0 = dWih0; pd.Whh0 = dWhh0; pd.b0 = db0;
  pd.Wih1 = dWih1; pd.Whh1 = dWhh1; pd.b1 = db1;
  pd.flags = flagsD;
  seq_kernel<1><<<dim3(NWG), dim3(NTHR), 0, stream>>>(pd);
}

// Round 4
// 36184.872 us; speedup vs baseline: 1.2710x; 1.2710x over previous
//
#include <hip/hip_runtime.h>

// Seq2Seq LSTM (H=1024, B=64, T_enc=T_dec=512), persistent-grid kernels.
// Inputs/outputs FLOAT32; tf_mask int32. f16 MFMA 16x16x32, f32 state.
// 256 WGs x 256 thr; WG w owns hidden units 4w..4w+3 (16 gate cols), all 64
// batches. 2 grid barriers per timestep.
//
// Coherence: cross-WG data (h ping-pong, predpart, flags) moves via
// system-scope relaxed atomics -> global_load/store sc0 sc1 (bypass L1/L2,
// served by shared LLC). Barrier needs no cache-flush fences, BUT each wave
// must drain vmcnt(0) before the barrier: relaxed atomic stores are NOT
// auto-drained by __syncthreads (round-3 race, absmax 6.1e-4). Explicit
// s_waitcnt vmcnt(0) at gbar entry restores store-visibility-before-flag.

#define HD 1024
#define BB 64
#define TT 512
#define NWG 256
#define NTHR 256

typedef _Float16 f16x8 __attribute__((ext_vector_type(8)));
typedef float f32x4 __attribute__((ext_vector_type(4)));
typedef unsigned long long u64;

struct KP {
  const float* seq;   // prev (enc) or nxt (dec), [B][T]
  const int* mask;    // [T] int32 (decoder only)
  const float* Wih0;  // [4096]
  const float* Whh0;  // [4096][1024]
  const float* b0;    // [4096]
  const float* Wih1;  // [4096][1024]
  const float* Whh1;  // [4096][1024]
  const float* b1;    // [4096]
  const float* fcW;   // [1024]
  const float* fcb;   // [1]
  _Float16* h0buf;    // [2][B][H] f16 ping-pong (coherent access)
  _Float16* h1buf;    // [2][B][H]
  float* c0buf;       // [B][H] f32 (enc->dec handoff, plain + dispatch flush)
  float* c1buf;       // [B][H]
  float* predpart;    // [2][16][B] f32 (coherent access)
  int* flags;         // [NWG]
  float* out;         // [B][T] f32
};

__device__ __forceinline__ float sigm(float x) { return 1.0f / (1.0f + expf(-x)); }

// ---- system-coherent (sc0 sc1) accessors: served by LLC ----
__device__ __forceinline__ u64 cload_u64(const void* p) {
  return __hip_atomic_load((const u64*)p, __ATOMIC_RELAXED, __HIP_MEMORY_SCOPE_SYSTEM);
}
__device__ __forceinline__ void cstore_u64(void* p, u64 v) {
  __hip_atomic_store((u64*)p, v, __ATOMIC_RELAXED, __HIP_MEMORY_SCOPE_SYSTEM);
}
__device__ __forceinline__ float cload_f32(const float* p) {
  return __hip_atomic_load(p, __ATOMIC_RELAXED, __HIP_MEMORY_SCOPE_SYSTEM);
}
__device__ __forceinline__ void cstore_f32(float* p, float v) {
  __hip_atomic_store(p, v, __ATOMIC_RELAXED, __HIP_MEMORY_SCOPE_SYSTEM);
}
__device__ __forceinline__ f16x8 cload_a(const _Float16* p) {
  union { u64 q[2]; f16x8 v; } c;
  c.q[0] = cload_u64(p);
  c.q[1] = cload_u64(p + 4);
  return c.v;
}

// Grid barrier: per-WG flag (monotone epoch), wave0 polls all 256 flags.
// EVERY wave drains its own VMEM (incl. relaxed sc0sc1 stores) before the
// entry barrier, so flag-set implies all WG stores are LLC-visible.
__device__ __forceinline__ void gbar(int* flags, int epoch) {
  asm volatile("s_waitcnt vmcnt(0)" ::: "memory");
  __syncthreads();
  if (threadIdx.x == 0) {
    __hip_atomic_store(&flags[blockIdx.x], epoch, __ATOMIC_RELAXED, __HIP_MEMORY_SCOPE_SYSTEM);
  }
  if (threadIdx.x < 64) {
#pragma unroll
    for (int i = 0; i < NWG / 64; ++i) {
      int idx = (int)threadIdx.x + i * 64;
      while (__hip_atomic_load(&flags[idx], __ATOMIC_RELAXED, __HIP_MEMORY_SCOPE_SYSTEM) < epoch)
        __builtin_amdgcn_s_sleep(1);
    }
  }
  asm volatile("" ::: "memory");
  __syncthreads();
}

__global__ void init_kernel(_Float16* h0, _Float16* h1, float* predpart, int* fe, int* fd) {
  int i = blockIdx.x * blockDim.x + threadIdx.x;
  int stride = gridDim.x * blockDim.x;
  for (int j = i; j < 2 * BB * HD; j += stride) {
    h0[j] = (_Float16)0.0f;
    h1[j] = (_Float16)0.0f;
  }
  for (int j = i; j < 2 * 16 * BB; j += stride) predpart[j] = 0.0f;
  if (i < NWG) {
    fe[i] = 0;
    fd[i] = 0;
  }
}

template <int IS_DEC>
__global__ __launch_bounds__(NTHR, 1) void seq_kernel(KP p) {
  // LDS: layer-1 weights (Wih1, Whh1), fragment-swizzled: [mat][kchunk][lane][8 f16]
  __shared__ _Float16 ldsW[2][32][64][8];  // 65536 B

  const int tid = threadIdx.x;
  const int wg = blockIdx.x;
  const int wave = tid >> 6;
  const int lane = tid & 63;
  const int n = lane & 15;      // MFMA col (N) / A row (M) index
  const int q = lane >> 4;      // quad
  const int gidx = n & 3;       // gate index within unit (i,f,g,o)
  const int u = n >> 2;         // local unit 0..3
  const int unitG = wg * 4 + u; // global hidden unit
  const int rowG = gidx * HD + unitG;  // row of W / bias for this lane's col
  const int koff = q * 8;
  const int arow = wave * 16 + n;      // batch row for A fragments

  // ---- one-time: stage layer-1 weights into LDS (f32 -> f16, swizzled) ----
  for (int g = tid; g < 4096; g += NTHR) {
    int mat = g >> 11;
    int gg = g & 2047;
    int kc = gg >> 6;
    int lv = gg & 63;
    int nn = lv & 15, qq = lv >> 4;
    int rG = (nn & 3) * HD + (wg * 4 + (nn >> 2));
    const float* src = (mat == 0 ? p.Wih1 : p.Whh1) + rG * HD + kc * 32 + qq * 8;
#pragma unroll
    for (int j = 0; j < 8; ++j) ldsW[mat][kc][lv][j] = (_Float16)src[j];
  }

  // ---- one-time: layer-0 hidden weights as register B-fragments (128 VGPRs) ----
  f16x8 wf0[32];
#pragma unroll
  for (int kc = 0; kc < 32; ++kc) {
    const float* src = p.Whh0 + rowG * HD + kc * 32 + koff;
    f16x8 v;
#pragma unroll
    for (int j = 0; j < 8; ++j) v[j] = (_Float16)src[j];
    wf0[kc] = v;
  }

  const float bias0 = p.b0[rowG];
  const float bias1 = p.b1[rowG];
  const float wih0 = p.Wih0[rowG];
  const float fcw = p.fcW[unitG];
  const float fcb = p.fcb[0];

  float c0r[4], c1r[4];
#pragma unroll
  for (int r = 0; r < 4; ++r) {
    if (IS_DEC) {
      int b = wave * 16 + q * 4 + r;
      c0r[r] = p.c0buf[b * HD + unitG];
      c1r[r] = p.c1buf[b * HD + unitG];
    } else {
      c0r[r] = 0.0f;
      c1r[r] = 0.0f;
    }
  }
  __syncthreads();

  int epoch = 1;
  for (int t = 0; t < TT; ++t) {
    const int wp = t & 1;
    _Float16* h0w = p.h0buf + wp * (BB * HD);
    const _Float16* h0r = p.h0buf + (1 - wp) * (BB * HD);
    _Float16* h1w = p.h1buf + wp * (BB * HD);
    const _Float16* h1r = p.h1buf + (1 - wp) * (BB * HD);

    // ================= layer 0 =================
    f32x4 acc = {0.0f, 0.0f, 0.0f, 0.0f};
    {
      const _Float16* Ap = h0r + arow * HD + koff;
#pragma unroll
      for (int kc = 0; kc < 32; ++kc) {
        f16x8 a = cload_a(Ap + kc * 32);
        acc = __builtin_amdgcn_mfma_f32_16x16x32_f16(a, wf0[kc], acc, 0, 0, 0);
      }
    }

    float xv[4];
    if (!IS_DEC) {
#pragma unroll
      for (int r = 0; r < 4; ++r) {
        int b = wave * 16 + q * 4 + r;
        xv[r] = p.seq[b * TT + t];
      }
    } else {
      if (t == 0) {
#pragma unroll
        for (int r = 0; r < 4; ++r) xv[r] = 0.0f;
      } else if (p.mask[t - 1] != 0) {
#pragma unroll
        for (int r = 0; r < 4; ++r) {
          int b = wave * 16 + q * 4 + r;
          xv[r] = p.seq[b * TT + (t - 1)];
        }
      } else {
        const float* pp = p.predpart + ((t - 1) & 1) * (16 * BB);
#pragma unroll
        for (int r = 0; r < 4; ++r) {
          int b = wave * 16 + q * 4 + r;
          float s = 0.0f;
#pragma unroll
          for (int j3 = 0; j3 < 4; ++j3) s += cload_f32(pp + (gidx * 4 + j3) * BB + b);
          s += __shfl_xor(s, 1);
          s += __shfl_xor(s, 2);
          xv[r] = s + fcb;
        }
      }
      // WG0 writes out[:, t-1] (pred of previous step, now fully reduced)
      if (wg == 0 && t > 0 && tid < BB) {
        const float* pp = p.predpart + ((t - 1) & 1) * (16 * BB);
        float s = fcb;
#pragma unroll
        for (int j2 = 0; j2 < 16; ++j2) s += cload_f32(pp + j2 * BB + tid);
        p.out[tid * TT + (t - 1)] = s;
      }
    }

#pragma unroll
    for (int r = 0; r < 4; ++r) {
      float v = acc[r] + bias0 + xv[r] * wih0;
      float v1 = __shfl_xor(v, 1);
      float v2 = __shfl_xor(v, 2);
      float v3 = __shfl_xor(v, 3);
      float gi = (gidx == 0) ? v : (gidx == 1) ? v1 : (gidx == 2) ? v2 : v3;
      float gf = (gidx == 1) ? v : (gidx == 0) ? v1 : (gidx == 3) ? v2 : v3;
      float gg = (gidx == 2) ? v : (gidx == 3) ? v1 : (gidx == 0) ? v2 : v3;
      float go = (gidx == 3) ? v : (gidx == 2) ? v1 : (gidx == 1) ? v2 : v3;
      float cn = sigm(gf) * c0r[r] + sigm(gi) * tanhf(gg);
      float hn = sigm(go) * tanhf(cn);
      c0r[r] = cn;  // hn identical across the 4 gate lanes of a unit
      // pack 4 units' h (lanes n=0,4,8,12) into one u64, store from lane n==0
      unsigned short hb = __builtin_bit_cast(unsigned short, (_Float16)hn);
      unsigned other = (unsigned)__shfl_xor((int)(unsigned)hb, 4);
      unsigned pair = (unsigned)hb | (other << 16);
      unsigned hi = (unsigned)__shfl_xor((int)pair, 8);
      u64 full = (u64)pair | ((u64)hi << 32);
      if (n == 0) {
        int b = wave * 16 + q * 4 + r;
        cstore_u64(&h0w[b * HD + wg * 4], full);
      }
    }
    gbar(p.flags, epoch++);

    // ================= layer 1 =================
    f32x4 acc2 = {0.0f, 0.0f, 0.0f, 0.0f};
    {
      const _Float16* Ax = h0w + arow * HD + koff;  // x-input = h0(t)
      const _Float16* Ah = h1r + arow * HD + koff;  // h-input = h1(t-1)
#pragma unroll
      for (int kc = 0; kc < 32; ++kc) {
        f16x8 a0 = cload_a(Ax + kc * 32);
        f16x8 b0 = *(const f16x8*)(&ldsW[0][kc][lane][0]);
        acc2 = __builtin_amdgcn_mfma_f32_16x16x32_f16(a0, b0, acc2, 0, 0, 0);
        f16x8 a1 = cload_a(Ah + kc * 32);
        f16x8 b1 = *(const f16x8*)(&ldsW[1][kc][lane][0]);
        acc2 = __builtin_amdgcn_mfma_f32_16x16x32_f16(a1, b1, acc2, 0, 0, 0);
      }
    }

    // zero the OTHER predpart parity (safe: its readers finished last phase)
    if (IS_DEC && wg == 0) {
      float* pz = p.predpart + (1 - (t & 1)) * (16 * BB);
      for (int i2 = tid; i2 < 16 * BB; i2 += NTHR) cstore_f32(pz + i2, 0.0f);
    }

#pragma unroll
    for (int r = 0; r < 4; ++r) {
      float v = acc2[r] + bias1;
      float v1 = __shfl_xor(v, 1);
      float v2 = __shfl_xor(v, 2);
      float v3 = __shfl_xor(v, 3);
      float gi = (gidx == 0) ? v : (gidx == 1) ? v1 : (gidx == 2) ? v2 : v3;
      float gf = (gidx == 1) ? v : (gidx == 0) ? v1 : (gidx == 3) ? v2 : v3;
      float gg = (gidx == 2) ? v : (gidx == 3) ? v1 : (gidx == 0) ? v2 : v3;
      float go = (gidx == 3) ? v : (gidx == 2) ? v1 : (gidx == 1) ? v2 : v3;
      float cn = sigm(gf) * c1r[r] + sigm(gi) * tanhf(gg);
      float hn = sigm(go) * tanhf(cn);
      c1r[r] = cn;
      unsigned short hb = __builtin_bit_cast(unsigned short, (_Float16)hn);
      unsigned other = (unsigned)__shfl_xor((int)(unsigned)hb, 4);
      unsigned pair = (unsigned)hb | (other << 16);
      unsigned hi = (unsigned)__shfl_xor((int)pair, 8);
      u64 full = (u64)pair | ((u64)hi << 32);
      if (n == 0) {
        int b = wave * 16 + q * 4 + r;
        cstore_u64(&h1w[b * HD + wg * 4], full);
      }
      if (IS_DEC) {
        // fc partial: sum over this WG's 4 units, 16-group atomics
        float pl = (gidx == 0) ? hn * fcw : 0.0f;
        pl += __shfl_xor(pl, 1);
        pl += __shfl_xor(pl, 2);
        pl += __shfl_xor(pl, 4);
        pl += __shfl_xor(pl, 8);
        if (n == 0) {
          int b = wave * 16 + q * 4 + r;
          atomicAdd(p.predpart + (t & 1) * (16 * BB) + (wg >> 4) * BB + b, pl);
        }
      }
    }
    gbar(p.flags, epoch++);
  }

  if (!IS_DEC) {
    // hand final c-states to the decoder (plain stores; end-of-dispatch
    // writeback makes them visible to the next kernel — verified round 2)
    if (gidx == 0) {
#pragma unroll
      for (int r = 0; r < 4; ++r) {
        int b = wave * 16 + q * 4 + r;
        p.c0buf[b * HD + unitG] = c0r[r];
        p.c1buf[b * HD + unitG] = c1r[r];
      }
    }
  } else {
    // final pred (t = 511)
    if (wg == 0 && tid < BB) {
      const float* pp = p.predpart + ((TT - 1) & 1) * (16 * BB);
      float s = fcb;
#pragma unroll
      for (int j2 = 0; j2 < 16; ++j2) s += cload_f32(pp + j2 * BB + tid);
      p.out[tid * TT + (TT - 1)] = s;
    }
  }
}

extern "C" void kernel_launch(void* const* d_in, const int* in_sizes, int n_in,
                              void* d_out, int out_size, void* d_ws, size_t ws_size,
                              hipStream_t stream) {
  (void)in_sizes; (void)n_in; (void)out_size; (void)ws_size;
  const float* prev = (const float*)d_in[0];
  const float* nxt = (const float*)d_in[1];
  const int* mask = (const int*)d_in[2];
  const float* eWih0 = (const float*)d_in[3];
  const float* eWhh0 = (const float*)d_in[4];
  const float* eb0 = (const float*)d_in[5];
  const float* eWih1 = (const float*)d_in[6];
  const float* eWhh1 = (const float*)d_in[7];
  const float* eb1 = (const float*)d_in[8];
  const float* dWih0 = (const float*)d_in[9];
  const float* dWhh0 = (const float*)d_in[10];
  const float* db0 = (const float*)d_in[11];
  const float* dWih1 = (const float*)d_in[12];
  const float* dWhh1 = (const float*)d_in[13];
  const float* db1 = (const float*)d_in[14];
  const float* fcW = (const float*)d_in[15];
  const float* fcb = (const float*)d_in[16];

  char* w = (char*)d_ws;
  _Float16* h0buf = (_Float16*)w; w += 2 * BB * HD * 2;
  _Float16* h1buf = (_Float16*)w; w += 2 * BB * HD * 2;
  float* c0buf = (float*)w; w += BB * HD * 4;
  float* c1buf = (float*)w; w += BB * HD * 4;
  float* predpart = (float*)w; w += 2 * 16 * BB * 4;
  int* flagsE = (int*)w; w += NWG * 4;
  int* flagsD = (int*)w; w += NWG * 4;

  init_kernel<<<dim3(128), dim3(256), 0, stream>>>(h0buf, h1buf, predpart, flagsE, flagsD);

  KP pe;
  pe.seq = prev; pe.mask = mask;
  pe.Wih0 = eWih0; pe.Whh0 = eWhh0; pe.b0 = eb0;
  pe.Wih1 = eWih1; pe.Whh1 = eWhh1; pe.b1 = eb1;
  pe.fcW = fcW; pe.fcb = fcb;
  pe.h0buf = h0buf; pe.h1buf = h1buf;
  pe.c0buf = c0buf; pe.c1buf = c1buf;
  pe.predpart = predpart; pe.flags = flagsE;
  pe.out = (float*)d_out;
  seq_kernel<0><<<dim3(NWG), dim3(NTHR), 0, stream>>>(pe);

  KP pd = pe;
  pd.seq = nxt;
  pd.Wih0 = dWih0; pd.Whh0 = dWhh0; pd.b0 = db0;
  pd.Wih1 = dWih1; pd.Whh1 = dWhh1; pd.b1 = db1;
  pd.flags = flagsD;
  seq_kernel<1><<<dim3(NWG), dim3(NTHR), 0, stream>>>(pd);
}

// Round 5
// 20039.775 us; speedup vs baseline: 2.2950x; 1.8057x over previous
//
#include <hip/hip_runtime.h>

// Seq2Seq LSTM (H=1024, B=64, T=512), persistent-grid, f16 MFMA, f32 state.
// Round-5 structure:
//  - h ping-pong buffers stored in MFMA-A-fragment-swizzled order:
//      hs[wv][kc][lane=(q<<4)|n][j] = h[batch=wv*16+n][unit=kc*32+q*8+j]
//    so consumer wave-loads are fully contiguous (512 B/instr, full lines).
//  - layer-1 stashes its h0(t) A-fragments in registers (haf[32]); layer-0
//    of step t+1 reuses them -> layer-0 phase has ZERO global h loads.
//  - encoder: 1 grid barrier/step (layer-0 consumes nothing from layer-1).
//    decoder: barrier-B only when pred feedback is needed (mask[t]==0) or
//    at the final step. Epoch predicate is grid-uniform (depends on mask[t]).
//  - cross-WG traffic via system-scope relaxed atomics (sc0sc1, LLC-coherent);
//    gbar drains vmcnt(0) per-wave before flag-set (round-3 lesson).

#define HD 1024
#define BB 64
#define TT 512
#define NWG 256
#define NTHR 256

typedef _Float16 f16x8 __attribute__((ext_vector_type(8)));
typedef float f32x4 __attribute__((ext_vector_type(4)));
typedef unsigned long long u64;

struct KP {
  const float* seq;
  const int* mask;
  const float* Wih0;
  const float* Whh0;
  const float* b0;
  const float* Wih1;
  const float* Whh1;
  const float* b1;
  const float* fcW;
  const float* fcb;
  _Float16* h0buf;   // [2][4][32][64][8] swizzled f16
  _Float16* h1buf;
  float* c0buf;
  float* c1buf;
  float* predpart;   // [2][16][B]
  int* flags;
  float* out;
};

__device__ __forceinline__ float sigm(float x) { return 1.0f / (1.0f + expf(-x)); }

__device__ __forceinline__ u64 cload_u64(const void* p) {
  return __hip_atomic_load((const u64*)p, __ATOMIC_RELAXED, __HIP_MEMORY_SCOPE_SYSTEM);
}
__device__ __forceinline__ void cstore_u64(void* p, u64 v) {
  __hip_atomic_store((u64*)p, v, __ATOMIC_RELAXED, __HIP_MEMORY_SCOPE_SYSTEM);
}
__device__ __forceinline__ float cload_f32(const float* p) {
  return __hip_atomic_load(p, __ATOMIC_RELAXED, __HIP_MEMORY_SCOPE_SYSTEM);
}
__device__ __forceinline__ void cstore_f32(float* p, float v) {
  __hip_atomic_store(p, v, __ATOMIC_RELAXED, __HIP_MEMORY_SCOPE_SYSTEM);
}
__device__ __forceinline__ f16x8 cload_a(const _Float16* p) {
  union { u64 q[2]; f16x8 v; } c;
  c.q[0] = cload_u64(p);
  c.q[1] = cload_u64(p + 4);
  return c.v;
}

__device__ __forceinline__ void gbar(int* flags, int epoch) {
  asm volatile("s_waitcnt vmcnt(0)" ::: "memory");
  __syncthreads();
  if (threadIdx.x == 0) {
    __hip_atomic_store(&flags[blockIdx.x], epoch, __ATOMIC_RELAXED, __HIP_MEMORY_SCOPE_SYSTEM);
  }
  if (threadIdx.x < 64) {
#pragma unroll
    for (int i = 0; i < NWG / 64; ++i) {
      int idx = (int)threadIdx.x + i * 64;
      while (__hip_atomic_load(&flags[idx], __ATOMIC_RELAXED, __HIP_MEMORY_SCOPE_AGENT) < epoch)
        __builtin_amdgcn_s_sleep(1);
    }
  }
  asm volatile("" ::: "memory");
  __syncthreads();
}

__global__ void init_kernel(_Float16* h0, _Float16* h1, float* predpart, int* fe, int* fd) {
  int i = blockIdx.x * blockDim.x + threadIdx.x;
  int stride = gridDim.x * blockDim.x;
  for (int j = i; j < 2 * BB * HD; j += stride) {
    h0[j] = (_Float16)0.0f;
    h1[j] = (_Float16)0.0f;
  }
  for (int j = i; j < 2 * 16 * BB; j += stride) predpart[j] = 0.0f;
  if (i < NWG) {
    fe[i] = 0;
    fd[i] = 0;
  }
}

template <int IS_DEC>
__global__ __launch_bounds__(NTHR, 1) void seq_kernel(KP p) {
  __shared__ _Float16 ldsW[2][32][64][8];  // 64 KB: layer-1 W fragments

  const int tid = threadIdx.x;
  const int wg = blockIdx.x;
  const int wave = tid >> 6;
  const int lane = tid & 63;
  const int n = lane & 15;
  const int q = lane >> 4;
  const int gidx = n & 3;
  const int u = n >> 2;
  const int unitG = wg * 4 + u;
  const int rowG = gidx * HD + unitG;
  const int koff = q * 8;

  // swizzled-store constants for this WG's 4 units (wg*4 .. wg*4+3):
  const int kc0 = wg >> 3;          // unit>>5
  const int q0 = (wg >> 1) & 3;     // (unit>>3)&3
  const int j8b = (wg & 1) * 4;     // unit&7 base
  // element offset of this lane's store slot (valid when q==q0):
  const int stoff = (((wave * 32 + kc0) << 6) + (q0 << 4) + n) * 8 + j8b;
  // bpermute source-lane base for gathering 4 units of batch-row n:
  const int Lb = ((n >> 2) << 4) | (n & 3);
  // consumer A-fragment load offset (elements):
  const int aoff = ((wave * 32) << 6 | lane) * 8;

  // ---- stage layer-1 weights into LDS (fragment-swizzled) ----
  for (int g = tid; g < 4096; g += NTHR) {
    int mat = g >> 11;
    int gg = g & 2047;
    int kc = gg >> 6;
    int lv = gg & 63;
    int nn = lv & 15, qq = lv >> 4;
    int rG = (nn & 3) * HD + (wg * 4 + (nn >> 2));
    const float* src = (mat == 0 ? p.Wih1 : p.Whh1) + rG * HD + kc * 32 + qq * 8;
#pragma unroll
    for (int j = 0; j < 8; ++j) ldsW[mat][kc][lv][j] = (_Float16)src[j];
  }

  // ---- layer-0 hidden weights as register B-fragments ----
  f16x8 wf0[32];
#pragma unroll
  for (int kc = 0; kc < 32; ++kc) {
    const float* src = p.Whh0 + rowG * HD + kc * 32 + koff;
    f16x8 v;
#pragma unroll
    for (int j = 0; j < 8; ++j) v[j] = (_Float16)src[j];
    wf0[kc] = v;
  }

  const float bias0 = p.b0[rowG];
  const float bias1 = p.b1[rowG];
  const float wih0 = p.Wih0[rowG];
  const float fcw = p.fcW[unitG];
  const float fcb = p.fcb[0];

  float c0r[4], c1r[4];
#pragma unroll
  for (int r = 0; r < 4; ++r) {
    if (IS_DEC) {
      int b = wave * 16 + q * 4 + r;
      c0r[r] = p.c0buf[b * HD + unitG];
      c1r[r] = p.c1buf[b * HD + unitG];
    } else {
      c0r[r] = 0.0f;
      c1r[r] = 0.0f;
    }
  }
  __syncthreads();

  // ---- bootstrap haf = h0(prev) from parity-1 buffer (zeros for encoder,
  //      encoder-final h0 for decoder) ----
  f16x8 haf[32];
  {
    const _Float16* hb = p.h0buf + BB * HD + aoff;
#pragma unroll
    for (int kc = 0; kc < 32; ++kc) haf[kc] = cload_a(hb + kc * 512);
  }

  int epoch = 1;
  for (int t = 0; t < TT; ++t) {
    const int wp = t & 1;
    _Float16* h0w = p.h0buf + wp * (BB * HD);
    _Float16* h1w = p.h1buf + wp * (BB * HD);
    const _Float16* h1r = p.h1buf + (1 - wp) * (BB * HD);

    // ================= layer 0 (no global h loads: haf in registers) ======
    f32x4 acc = {0.0f, 0.0f, 0.0f, 0.0f};
#pragma unroll
    for (int kc = 0; kc < 32; ++kc)
      acc = __builtin_amdgcn_mfma_f32_16x16x32_f16(haf[kc], wf0[kc], acc, 0, 0, 0);

    float xv[4];
    if (!IS_DEC) {
#pragma unroll
      for (int r = 0; r < 4; ++r) {
        int b = wave * 16 + q * 4 + r;
        xv[r] = p.seq[b * TT + t];
      }
    } else {
      if (t == 0) {
#pragma unroll
        for (int r = 0; r < 4; ++r) xv[r] = 0.0f;
      } else if (p.mask[t - 1] != 0) {
#pragma unroll
        for (int r = 0; r < 4; ++r) {
          int b = wave * 16 + q * 4 + r;
          xv[r] = p.seq[b * TT + (t - 1)];
        }
      } else {
        const float* pp = p.predpart + ((t - 1) & 1) * (16 * BB);
#pragma unroll
        for (int r = 0; r < 4; ++r) {
          int b = wave * 16 + q * 4 + r;
          float s = 0.0f;
#pragma unroll
          for (int j3 = 0; j3 < 4; ++j3) s += cload_f32(pp + (gidx * 4 + j3) * BB + b);
          s += __shfl_xor(s, 1);
          s += __shfl_xor(s, 2);
          xv[r] = s + fcb;
        }
      }
    }

    float hn0[4];
#pragma unroll
    for (int r = 0; r < 4; ++r) {
      float v = acc[r] + bias0 + xv[r] * wih0;
      float v1 = __shfl_xor(v, 1);
      float v2 = __shfl_xor(v, 2);
      float v3 = __shfl_xor(v, 3);
      float gi = (gidx == 0) ? v : (gidx == 1) ? v1 : (gidx == 2) ? v2 : v3;
      float gf = (gidx == 1) ? v : (gidx == 0) ? v1 : (gidx == 3) ? v2 : v3;
      float gg = (gidx == 2) ? v : (gidx == 3) ? v1 : (gidx == 0) ? v2 : v3;
      float go = (gidx == 3) ? v : (gidx == 2) ? v1 : (gidx == 1) ? v2 : v3;
      float cn = sigm(gf) * c0r[r] + sigm(gi) * tanhf(gg);
      hn0[r] = sigm(go) * tanhf(cn);
      c0r[r] = cn;
    }
    // swizzled h0 store via bpermute gather (4 units of batch-row n)
    {
      int hb0 = (int)(unsigned)__builtin_bit_cast(unsigned short, (_Float16)hn0[0]);
      int hb1 = (int)(unsigned)__builtin_bit_cast(unsigned short, (_Float16)hn0[1]);
      int hb2 = (int)(unsigned)__builtin_bit_cast(unsigned short, (_Float16)hn0[2]);
      int hb3 = (int)(unsigned)__builtin_bit_cast(unsigned short, (_Float16)hn0[3]);
      int iv = (gidx == 0) ? hb0 : (gidx == 1) ? hb1 : (gidx == 2) ? hb2 : hb3;
      int w0 = __shfl(iv, Lb);
      int w1 = __shfl(iv, Lb + 4);
      int w2 = __shfl(iv, Lb + 8);
      int w3 = __shfl(iv, Lb + 12);
      u64 lo = (unsigned)(w0 & 0xFFFF) | ((unsigned)(w1 & 0xFFFF) << 16);
      u64 hi = (unsigned)(w2 & 0xFFFF) | ((unsigned)(w3 & 0xFFFF) << 16);
      u64 pk = lo | (hi << 32);
      if (q == q0) cstore_u64(h0w + stoff, pk);
    }
    gbar(p.flags, epoch++);  // barrier A

    // ================= layer 1 =================
    // decoder bookkeeping (safe: >=1 barrier after l1(t-1) atomics)
    if (IS_DEC && wg == 0 && t > 0 && tid < BB) {
      const float* pp = p.predpart + ((t - 1) & 1) * (16 * BB);
      float s = fcb;
#pragma unroll
      for (int j2 = 0; j2 < 16; ++j2) s += cload_f32(pp + j2 * BB + tid);
      p.out[tid * TT + (t - 1)] = s;
      asm volatile("" ::: "memory");
      float* pz = p.predpart + ((t - 1) & 1) * (16 * BB);
#pragma unroll
      for (int j2 = 0; j2 < 16; ++j2) cstore_f32(pz + j2 * BB + tid, 0.0f);
    }

    f32x4 acc2 = {0.0f, 0.0f, 0.0f, 0.0f};
    {
      const _Float16* Ax = h0w + aoff;
      const _Float16* Ah = h1r + aoff;
#pragma unroll
      for (int kc = 0; kc < 32; ++kc) {
        f16x8 a0 = cload_a(Ax + kc * 512);
        haf[kc] = a0;  // register-carry for layer-0 of step t+1
        f16x8 b0 = *(const f16x8*)(&ldsW[0][kc][lane][0]);
        acc2 = __builtin_amdgcn_mfma_f32_16x16x32_f16(a0, b0, acc2, 0, 0, 0);
        f16x8 a1 = cload_a(Ah + kc * 512);
        f16x8 b1 = *(const f16x8*)(&ldsW[1][kc][lane][0]);
        acc2 = __builtin_amdgcn_mfma_f32_16x16x32_f16(a1, b1, acc2, 0, 0, 0);
      }
    }

    float hn1[4];
#pragma unroll
    for (int r = 0; r < 4; ++r) {
      float v = acc2[r] + bias1;
      float v1 = __shfl_xor(v, 1);
      float v2 = __shfl_xor(v, 2);
      float v3 = __shfl_xor(v, 3);
      float gi = (gidx == 0) ? v : (gidx == 1) ? v1 : (gidx == 2) ? v2 : v3;
      float gf = (gidx == 1) ? v : (gidx == 0) ? v1 : (gidx == 3) ? v2 : v3;
      float gg = (gidx == 2) ? v : (gidx == 3) ? v1 : (gidx == 0) ? v2 : v3;
      float go = (gidx == 3) ? v : (gidx == 2) ? v1 : (gidx == 1) ? v2 : v3;
      float cn = sigm(gf) * c1r[r] + sigm(gi) * tanhf(gg);
      float hn = sigm(go) * tanhf(cn);
      hn1[r] = hn;
      c1r[r] = cn;
      if (IS_DEC) {
        float pl = (gidx == 0) ? hn * fcw : 0.0f;
        pl += __shfl_xor(pl, 1);
        pl += __shfl_xor(pl, 2);
        pl += __shfl_xor(pl, 4);
        pl += __shfl_xor(pl, 8);
        if (n == 0) {
          int b = wave * 16 + q * 4 + r;
          atomicAdd(p.predpart + (t & 1) * (16 * BB) + (wg >> 4) * BB + b, pl);
        }
      }
    }
    // swizzled h1 store
    {
      int hb0 = (int)(unsigned)__builtin_bit_cast(unsigned short, (_Float16)hn1[0]);
      int hb1 = (int)(unsigned)__builtin_bit_cast(unsigned short, (_Float16)hn1[1]);
      int hb2 = (int)(unsigned)__builtin_bit_cast(unsigned short, (_Float16)hn1[2]);
      int hb3 = (int)(unsigned)__builtin_bit_cast(unsigned short, (_Float16)hn1[3]);
      int iv = (gidx == 0) ? hb0 : (gidx == 1) ? hb1 : (gidx == 2) ? hb2 : hb3;
      int w0 = __shfl(iv, Lb);
      int w1 = __shfl(iv, Lb + 4);
      int w2 = __shfl(iv, Lb + 8);
      int w3 = __shfl(iv, Lb + 12);
      u64 lo = (unsigned)(w0 & 0xFFFF) | ((unsigned)(w1 & 0xFFFF) << 16);
      u64 hi = (unsigned)(w2 & 0xFFFF) | ((unsigned)(w3 & 0xFFFF) << 16);
      u64 pk = lo | (hi << 32);
      if (q == q0) cstore_u64(h1w + stoff, pk);
    }

    // barrier B: encoder never; decoder only when pred feedback needed
    if (IS_DEC) {
      if (t == TT - 1 || p.mask[t] == 0) gbar(p.flags, epoch++);
    }
  }

  if (!IS_DEC) {
    if (gidx == 0) {
#pragma unroll
      for (int r = 0; r < 4; ++r) {
        int b = wave * 16 + q * 4 + r;
        p.c0buf[b * HD + unitG] = c0r[r];
        p.c1buf[b * HD + unitG] = c1r[r];
      }
    }
  } else {
    if (wg == 0 && tid < BB) {
      const float* pp = p.predpart + ((TT - 1) & 1) * (16 * BB);
      float s = fcb;
#pragma unroll
      for (int j2 = 0; j2 < 16; ++j2) s += cload_f32(pp + j2 * BB + tid);
      p.out[tid * TT + (TT - 1)] = s;
    }
  }
}

extern "C" void kernel_launch(void* const* d_in, const int* in_sizes, int n_in,
                              void* d_out, int out_size, void* d_ws, size_t ws_size,
                              hipStream_t stream) {
  (void)in_sizes; (void)n_in; (void)out_size; (void)ws_size;
  const float* prev = (const float*)d_in[0];
  const float* nxt = (const float*)d_in[1];
  const int* mask = (const int*)d_in[2];
  const float* eWih0 = (const float*)d_in[3];
  const float* eWhh0 = (const float*)d_in[4];
  const float* eb0 = (const float*)d_in[5];
  const float* eWih1 = (const float*)d_in[6];
  const float* eWhh1 = (const float*)d_in[7];
  const float* eb1 = (const float*)d_in[8];
  const float* dWih0 = (const float*)d_in[9];
  const float* dWhh0 = (const float*)d_in[10];
  const float* db0 = (const float*)d_in[11];
  const float* dWih1 = (const float*)d_in[12];
  const float* dWhh1 = (const float*)d_in[13];
  const float* db1 = (const float*)d_in[14];
  const float* fcW = (const float*)d_in[15];
  const float* fcb = (const float*)d_in[16];

  char* w = (char*)d_ws;
  _Float16* h0buf = (_Float16*)w; w += 2 * BB * HD * 2;
  _Float16* h1buf = (_Float16*)w; w += 2 * BB * HD * 2;
  float* c0buf = (float*)w; w += BB * HD * 4;
  float* c1buf = (float*)w; w += BB * HD * 4;
  float* predpart = (float*)w; w += 2 * 16 * BB * 4;
  int* flagsE = (int*)w; w += NWG * 4;
  int* flagsD = (int*)w; w += NWG * 4;

  init_kernel<<<dim3(128), dim3(256), 0, stream>>>(h0buf, h1buf, predpart, flagsE, flagsD);

  KP pe;
  pe.seq = prev; pe.mask = mask;
  pe.Wih0 = eWih0; pe.Whh0 = eWhh0; pe.b0 = eb0;
  pe.Wih1 = eWih1; pe.Whh1 = eWhh1; pe.b1 = eb1;
  pe.fcW = fcW; pe.fcb = fcb;
  pe.h0buf = h0buf; pe.h1buf = h1buf;
  pe.c0buf = c0buf; pe.c1buf = c1buf;
  pe.predpart = predpart; pe.flags = flagsE;
  pe.out = (float*)d_out;
  seq_kernel<0><<<dim3(NWG), dim3(NTHR), 0, stream>>>(pe);

  KP pd = pe;
  pd.seq = nxt;
  pd.Wih0 = dWih0; pd.Whh0 = dWhh0; pd.b0 = db0;
  pd.Wih1 = dWih1; pd.Whh1 = dWhh1; pd.b1 = db1;
  pd.flags = flagsD;
  seq_kernel<1><<<dim3(NWG), dim3(NTHR), 0, stream>>>(pd);
}